// Round 3
// baseline (156.599 us; speedup 1.0000x reference)
//
#include <hip/hip_runtime.h>
#include <math.h>

typedef float v2f __attribute__((ext_vector_type(2)));

#define NSUP 512
#define DLAT 128
#define DHID 512
#define DIN  64
#define BR   16
#define NTILE 256   // 4096 / BR

// ---------------- prep: transposes + packs + support trig + norms ----------------
__global__ __launch_bounds__(512) void prep_kernel(
    const float* __restrict__ x, const float* __restrict__ W1, const float* __restrict__ W2,
    const float* __restrict__ support,
    float* __restrict__ W1T, float* __restrict__ W2T, float* __restrict__ xpack,
    float4* __restrict__ scd, float* __restrict__ sn2)
{
    int idx = blockIdx.x * 512 + threadIdx.x;          // 512 x 512 = 262144
    {   // xpack[t][k][r] = x[t*16+r][k]   (writes coalesced)
        int t = idx >> 10, rem = idx & 1023, k = rem >> 4, r = rem & 15;
        xpack[idx] = x[((t << 4) | r) * DIN + k];
    }
    if (idx < DHID * DIN) {                 // W1 [512][64] -> W1T [64][512]
        int c = idx / DIN, k = idx % DIN;
        W1T[k * DHID + c] = W1[idx];
    }
    if (idx < DLAT * DHID) {
        int j = idx / DHID, k = idx % DHID;             // W2 -> W2T
        W2T[k * DLAT + j] = W2[idx];
        int s = idx & (NSUP - 1), i = idx >> 9;         // scd[i][s], writes coalesced
        float v = support[s * DLAT + i];
        scd[i * NSUP + s] = make_float4(v, cosf(0.5f * v), sinf(0.5f * v), 0.f);
    }
    if (idx < NSUP) {                       // ||s||^2 via float4
        const float4* sp = (const float4*)(support + idx * DLAT);
        float acc = 0.f;
        #pragma unroll 8
        for (int i4 = 0; i4 < DLAT / 4; i4++) {
            float4 v = sp[i4];
            acc = fmaf(v.x, v.x, fmaf(v.y, v.y, fmaf(v.z, v.z, fmaf(v.w, v.w, acc))));
        }
        sn2[idx] = acc;
    }
}

// ---------------- GEMM1: h = tanh(x @ W1^T + b1) ----------------
// grid 256 x 512. thread c = tid owns ALL 16 rows of hidden col c -> coalesced float4 stores.
__global__ __launch_bounds__(512) void gemm1_kernel(
    const float* __restrict__ W1T, const float* __restrict__ b1,
    const float* __restrict__ xpack, float* __restrict__ hpack)
{
    const int t = blockIdx.x;
    const int c = threadIdx.x;
    const float* __restrict__ xr = xpack + t * (DIN * BR);   // uniform base -> s_load

    v2f acc[8];
    #pragma unroll
    for (int q = 0; q < 8; q++) acc[q] = (v2f)(0.f);

    for (int k = 0; k < DIN; k++) {
        float w = W1T[k * DHID + c];
        v2f wv = {w, w};
        const float* xk = xr + k * BR;                       // uniform -> s_load_dwordx16
        #pragma unroll
        for (int q = 0; q < 8; q++) {
            v2f xv = {xk[2 * q], xk[2 * q + 1]};
            acc[q] = __builtin_elementwise_fma(xv, wv, acc[q]);
        }
    }
    float bb = b1[c];
    float hv[16];
    #pragma unroll
    for (int q = 0; q < 8; q++) {
        hv[2 * q]     = tanhf(acc[q].x + bb);
        hv[2 * q + 1] = tanhf(acc[q].y + bb);
    }
    float4* hp = (float4*)(hpack + t * (DHID * BR) + c * BR);  // 64B/thread contiguous
    hp[0] = make_float4(hv[0],  hv[1],  hv[2],  hv[3]);
    hp[1] = make_float4(hv[4],  hv[5],  hv[6],  hv[7]);
    hp[2] = make_float4(hv[8],  hv[9],  hv[10], hv[11]);
    hp[3] = make_float4(hv[12], hv[13], hv[14], hv[15]);
}

// ---------------- GEMM2: latent + trig, packed [t][i][rp*6]={l0,l1,a0,a1,b0,b1} ----------------
// grid 256 x 1024. thread: latent col j = tid&127, k-group g = tid>>7 (64 k each)
__global__ __launch_bounds__(1024) void gemm2_kernel(
    const float* __restrict__ W2T, const float* __restrict__ b2,
    const float* __restrict__ hpack, float4* __restrict__ rowpack, float* __restrict__ ln2s)
{
    __shared__ float part[8][DLAT][17];    // 69632 B
    __shared__ float tbuf[DLAT][49];       // 25088 B transpose buffer
    __shared__ float l2red[16][2];

    const int t = blockIdx.x;
    const int j = threadIdx.x & (DLAT - 1);
    const int g = threadIdx.x >> 7;
    const float* __restrict__ hrow = hpack + t * (DHID * BR);

    v2f acc[8];
    #pragma unroll
    for (int q = 0; q < 8; q++) acc[q] = (v2f)(0.f);

    for (int kk = 0; kk < 64; kk++) {
        int k = g * 64 + kk;
        float w = W2T[k * DLAT + j];
        v2f wv = {w, w};
        const float* hk = hrow + k * BR;               // uniform -> s_load_dwordx16
        #pragma unroll
        for (int q = 0; q < 8; q++) {
            v2f hv = {hk[2 * q], hk[2 * q + 1]};
            acc[q] = __builtin_elementwise_fma(hv, wv, acc[q]);
        }
    }
    #pragma unroll
    for (int q = 0; q < 8; q++) {
        part[g][j][2 * q]     = acc[q].x;
        part[g][j][2 * q + 1] = acc[q].y;
    }
    __syncthreads();

    const int rp = g;                                   // row-pair 0..7
    float s0 = 0.f, s1 = 0.f;
    #pragma unroll
    for (int g2 = 0; g2 < 8; g2++) {
        s0 += part[g2][j][2 * rp];
        s1 += part[g2][j][2 * rp + 1];
    }
    float bb = b2[j];
    float l0 = s0 + bb, l1 = s1 + bb;

    tbuf[j][rp * 6 + 0] = l0;
    tbuf[j][rp * 6 + 1] = l1;
    tbuf[j][rp * 6 + 2] = cosf(0.5f * l0);
    tbuf[j][rp * 6 + 3] = cosf(0.5f * l1);
    tbuf[j][rp * 6 + 4] = sinf(0.5f * l0);
    tbuf[j][rp * 6 + 5] = sinf(0.5f * l1);

    // ||l||^2 per row
    const int wv = threadIdx.x >> 6;
    float v0 = l0 * l0, v1 = l1 * l1;
    for (int off = 32; off; off >>= 1) { v0 += __shfl_down(v0, off); v1 += __shfl_down(v1, off); }
    if ((threadIdx.x & 63) == 0) { l2red[wv][0] = v0; l2red[wv][1] = v1; }
    __syncthreads();

    if (threadIdx.x < BR) {
        int r = threadIdx.x, p = r >> 1, sel = r & 1;
        ln2s[t * BR + r] = l2red[2 * p][sel] + l2red[2 * p + 1][sel];
    }
    // coalesced rowpack store: 1536 float4 per tile
    for (int w = threadIdx.x; w < DLAT * 48 / 4; w += 1024) {
        int i = w / 12, off = (w % 12) * 4;
        rowpack[t * 1536 + w] = make_float4(tbuf[i][off], tbuf[i][off + 1],
                                            tbuf[i][off + 2], tbuf[i][off + 3]);
    }
}

// ---------------- stage B: kernels + weighted support reduction ----------------
// grid 256 x 1024 (16 waves). half = wave>>3 picks i-range; lane+wave&7 -> support s.
__global__ __launch_bounds__(1024) void kernelB(
    const float4* __restrict__ scd, const float* __restrict__ sn2,
    const float* __restrict__ wts, const float* __restrict__ rowpack,
    const float* __restrict__ ln2s, float* __restrict__ out)
{
    __shared__ float c01[NSUP][17];     // half0 -> partials for rows 8..15 (8 dot | 8 prod)
    __shared__ float c10[NSUP][17];     // half1 -> partials for rows 0..7
    __shared__ float redw[16][8];

    const int t    = blockIdx.x;
    const int wv   = threadIdx.x >> 6;
    const int lane = threadIdx.x & 63;
    const int half = wv >> 3;
    const int s    = ((wv & 7) << 6) | lane;
    const int i0   = half * 64;

    const float* __restrict__ rp0 = rowpack + t * (DLAT * 48) + i0 * 48;  // uniform

    v2f dot[8], prod[8];
    #pragma unroll
    for (int q = 0; q < 8; q++) { dot[q] = (v2f)(0.f); prod[q] = (v2f)(1.f); }

    #pragma unroll 2
    for (int ii = 0; ii < 64; ii++) {
        float4 sc = scd[(i0 + ii) * NSUP + s];
        v2f sv = {sc.x, sc.x}, cv = {sc.y, sc.y}, dv = {sc.z, sc.z};
        const float* rp = rp0 + ii * 48;            // uniform -> 3x s_load_dwordx16
        #pragma unroll
        for (int q = 0; q < 8; q++) {
            v2f lv = {rp[6 * q],     rp[6 * q + 1]};
            v2f av = {rp[6 * q + 2], rp[6 * q + 3]};
            v2f bv = {rp[6 * q + 4], rp[6 * q + 5]};
            dot[q]  = __builtin_elementwise_fma(lv, sv, dot[q]);
            v2f tt  = __builtin_elementwise_fma(av, cv, bv * dv);
            prod[q] = prod[q] * tt;
        }
    }

    // exchange: each half publishes the OTHER half's row-range partials
    if (half == 0) {
        #pragma unroll
        for (int q = 4; q < 8; q++) {
            c01[s][2 * (q - 4)]         = dot[q].x;
            c01[s][2 * (q - 4) + 1]     = dot[q].y;
            c01[s][8 + 2 * (q - 4)]     = prod[q].x;
            c01[s][8 + 2 * (q - 4) + 1] = prod[q].y;
        }
    } else {
        #pragma unroll
        for (int q = 0; q < 4; q++) {
            c10[s][2 * q]         = dot[q].x;
            c10[s][2 * q + 1]     = dot[q].y;
            c10[s][8 + 2 * q]     = prod[q].x;
            c10[s][8 + 2 * q + 1] = prod[q].y;
        }
    }
    __syncthreads();

    // combine own 8 rows
    float dfull[8], pfull[8];
    if (half == 0) {
        #pragma unroll
        for (int q = 0; q < 4; q++) {
            dfull[2 * q]     = dot[q].x + c10[s][2 * q];
            dfull[2 * q + 1] = dot[q].y + c10[s][2 * q + 1];
            pfull[2 * q]     = prod[q].x * c10[s][8 + 2 * q];
            pfull[2 * q + 1] = prod[q].y * c10[s][8 + 2 * q + 1];
        }
    } else {
        #pragma unroll
        for (int q = 4; q < 8; q++) {
            dfull[2 * (q - 4)]     = dot[q].x + c01[s][2 * (q - 4)];
            dfull[2 * (q - 4) + 1] = dot[q].y + c01[s][2 * (q - 4) + 1];
            pfull[2 * (q - 4)]     = prod[q].x * c01[s][8 + 2 * (q - 4)];
            pfull[2 * (q - 4) + 1] = prod[q].y * c01[s][8 + 2 * (q - 4) + 1];
        }
    }

    float sn  = sn2[s];
    float wgt = wts[s];
    const float* lr = ln2s + t * BR + half * 8;     // uniform
    #pragma unroll
    for (int rr = 0; rr < 8; rr++) {
        float sq = lr[rr] + sn - 2.f * dfull[rr];
        float kc = __expf(-sq);
        float p  = pfull[rr];
        float v  = (0.5f * kc + 0.5f * (p * p)) * wgt;
        for (int off = 32; off; off >>= 1) v += __shfl_down(v, off);
        if (lane == 0) redw[wv][rr] = v;
    }
    __syncthreads();
    if (threadIdx.x < BR) {
        int h = threadIdx.x >> 3, rr = threadIdx.x & 7;
        float o = 0.f;
        #pragma unroll
        for (int w = 0; w < 8; w++) o += redw[h * 8 + w][rr];
        out[t * BR + h * 8 + rr] = o;
    }
}

// ---------------- launch ----------------
extern "C" void kernel_launch(void* const* d_in, const int* in_sizes, int n_in,
                              void* d_out, int out_size, void* d_ws, size_t ws_size,
                              hipStream_t stream) {
    const float* x       = (const float*)d_in[0];
    const float* W1      = (const float*)d_in[1];
    const float* b1      = (const float*)d_in[2];
    const float* W2      = (const float*)d_in[3];
    const float* b2      = (const float*)d_in[4];
    const float* support = (const float*)d_in[5];
    const float* wts     = (const float*)d_in[6];
    float* out = (float*)d_out;

    float* ws      = (float*)d_ws;
    float* W1T     = ws;                        // 32768
    float* W2T     = W1T + 32768;               // 65536
    float* xpack   = W2T + 65536;               // 262144
    float* hpack   = xpack + 262144;            // 2097152
    float* rowpack = hpack + 2097152;           // 1572864 (16B-aligned offset)
    float* ln2s    = rowpack + 1572864;         // 4096
    float* sn2     = ln2s + 4096;               // 512
    float4* scd    = (float4*)(sn2 + 512);      // 65536 float4 (16B-aligned offset)

    prep_kernel <<<512,  512, 0, stream>>>(x, W1, W2, support, W1T, W2T, xpack, scd, sn2);
    gemm1_kernel<<<NTILE, 512, 0, stream>>>(W1T, b1, xpack, hpack);
    gemm2_kernel<<<NTILE, 1024, 0, stream>>>(W2T, b2, hpack, (float4*)rowpack, ln2s);
    kernelB     <<<NTILE, 1024, 0, stream>>>(scd, sn2, wts, rowpack, ln2s, out);
}

// Round 4
// 69.576 us; speedup vs baseline: 2.2508x; 2.2508x over previous
//
#include <hip/hip_runtime.h>
#include <math.h>

typedef float v2f __attribute__((ext_vector_type(2)));

#define NSUP 512
#define DLAT 128
#define DHID 512
#define DIN  64
#define BR   16
#define NTILE 256   // 4096 / BR
#define RPSTRIDE 64 // rowpack row: [l16|a16|b16|pad16] floats, 256B

// ---------------- prep: transposes + packs + support trig + norms ----------------
__global__ __launch_bounds__(512) void prep_kernel(
    const float* __restrict__ x, const float* __restrict__ W1, const float* __restrict__ W2,
    const float* __restrict__ support,
    float* __restrict__ W1T, float* __restrict__ W2T, float* __restrict__ xpack,
    float4* __restrict__ scd, float* __restrict__ sn2)
{
    int idx = blockIdx.x * 512 + threadIdx.x;          // 512 x 512 = 262144
    {   // xpack[t][k][r] = x[t*16+r][k]   (writes coalesced)
        int t = idx >> 10, rem = idx & 1023, k = rem >> 4, r = rem & 15;
        xpack[idx] = x[((t << 4) | r) * DIN + k];
    }
    if (idx < DHID * DIN) {                 // W1 [512][64] -> W1T [64][512]
        int c = idx / DIN, k = idx % DIN;
        W1T[k * DHID + c] = W1[idx];
    }
    if (idx < DLAT * DHID) {
        int j = idx / DHID, k = idx % DHID;             // W2 -> W2T
        W2T[k * DLAT + j] = W2[idx];
        int s = idx & (NSUP - 1), i = idx >> 9;         // scd[i][s], writes coalesced
        float v = support[s * DLAT + i];
        scd[i * NSUP + s] = make_float4(v, cosf(0.5f * v), sinf(0.5f * v), 0.f);
    }
    if (idx < NSUP) {                       // ||s||^2 via float4
        const float4* sp = (const float4*)(support + idx * DLAT);
        float acc = 0.f;
        #pragma unroll 8
        for (int i4 = 0; i4 < DLAT / 4; i4++) {
            float4 v = sp[i4];
            acc = fmaf(v.x, v.x, fmaf(v.y, v.y, fmaf(v.z, v.z, fmaf(v.w, v.w, acc))));
        }
        sn2[idx] = acc;
    }
}

// ---------------- GEMM1: h = tanh(x @ W1^T + b1) ----------------
// grid 256 x 512. thread c owns hidden col c (16 rows); LDS-staged coalesced store.
__global__ __launch_bounds__(512) void gemm1_kernel(
    const float* __restrict__ W1T, const float* __restrict__ b1,
    const float* __restrict__ xpack, float* __restrict__ hpack)
{
    __shared__ float sh[DHID][17];                           // 34.8 KB
    const int t = blockIdx.x;
    const int c = threadIdx.x;
    const float* __restrict__ xr = xpack + t * (DIN * BR);   // uniform base -> s_load

    v2f acc[8];
    #pragma unroll
    for (int q = 0; q < 8; q++) acc[q] = (v2f)(0.f);

    for (int k = 0; k < DIN; k++) {
        float w = W1T[k * DHID + c];
        v2f wv = {w, w};
        const float* xk = xr + k * BR;                       // uniform -> s_load_dwordx16
        #pragma unroll
        for (int q = 0; q < 8; q++) {
            v2f xv = {xk[2 * q], xk[2 * q + 1]};
            acc[q] = __builtin_elementwise_fma(xv, wv, acc[q]);
        }
    }
    float bb = b1[c];
    #pragma unroll
    for (int q = 0; q < 8; q++) {
        sh[c][2 * q]     = tanhf(acc[q].x + bb);
        sh[c][2 * q + 1] = tanhf(acc[q].y + bb);
    }
    __syncthreads();
    // coalesced store: 2048 float4 per tile, 4 per thread
    float4* hp = (float4*)(hpack + t * (DHID * BR));
    #pragma unroll
    for (int w = threadIdx.x; w < DHID * BR / 4; w += 512) {
        int cc = w >> 2, r0 = (w & 3) * 4;
        hp[w] = make_float4(sh[cc][r0], sh[cc][r0 + 1], sh[cc][r0 + 2], sh[cc][r0 + 3]);
    }
}

// ---------------- GEMM2: latent + trig -> rowpack [t][i][64]={l16|a16|b16|pad} ----------------
// grid 256 x 1024. thread: latent col j = tid&127, k-group g = tid>>7 (64 k each)
__global__ __launch_bounds__(1024) void gemm2_kernel(
    const float* __restrict__ W2T, const float* __restrict__ b2,
    const float* __restrict__ hpack, float4* __restrict__ rowpack, float* __restrict__ ln2s)
{
    __shared__ float part[8][DLAT][17];    // 69632 B
    __shared__ float tbuf[DLAT][68];       // 34816 B transpose buffer (stride 68)
    __shared__ float l2red[16][2];

    const int t = blockIdx.x;
    const int j = threadIdx.x & (DLAT - 1);
    const int g = __builtin_amdgcn_readfirstlane(threadIdx.x >> 7);   // wave-uniform
    const float* __restrict__ hrow = hpack + t * (DHID * BR);

    v2f acc[8];
    #pragma unroll
    for (int q = 0; q < 8; q++) acc[q] = (v2f)(0.f);

    for (int kk = 0; kk < 64; kk++) {
        int k = g * 64 + kk;
        float w = W2T[k * DLAT + j];
        v2f wv = {w, w};
        const float* hk = hrow + k * BR;               // uniform -> s_load_dwordx16
        #pragma unroll
        for (int q = 0; q < 8; q++) {
            v2f hv = {hk[2 * q], hk[2 * q + 1]};
            acc[q] = __builtin_elementwise_fma(hv, wv, acc[q]);
        }
    }
    #pragma unroll
    for (int q = 0; q < 8; q++) {
        part[g][j][2 * q]     = acc[q].x;
        part[g][j][2 * q + 1] = acc[q].y;
    }
    __syncthreads();

    const int rp = g;                                   // row-pair 0..7
    float s0 = 0.f, s1 = 0.f;
    #pragma unroll
    for (int g2 = 0; g2 < 8; g2++) {
        s0 += part[g2][j][2 * rp];
        s1 += part[g2][j][2 * rp + 1];
    }
    float bb = b2[j];
    float l0 = s0 + bb, l1 = s1 + bb;

    tbuf[j][2 * rp]          = l0;
    tbuf[j][2 * rp + 1]      = l1;
    tbuf[j][16 + 2 * rp]     = cosf(0.5f * l0);
    tbuf[j][16 + 2 * rp + 1] = cosf(0.5f * l1);
    tbuf[j][32 + 2 * rp]     = sinf(0.5f * l0);
    tbuf[j][32 + 2 * rp + 1] = sinf(0.5f * l1);

    // ||l||^2 per row
    const int wv = threadIdx.x >> 6;
    float v0 = l0 * l0, v1 = l1 * l1;
    for (int off = 32; off; off >>= 1) { v0 += __shfl_down(v0, off); v1 += __shfl_down(v1, off); }
    if ((threadIdx.x & 63) == 0) { l2red[wv][0] = v0; l2red[wv][1] = v1; }
    __syncthreads();

    if (threadIdx.x < BR) {
        int r = threadIdx.x, p = r >> 1, sel = r & 1;
        ln2s[t * BR + r] = l2red[2 * p][sel] + l2red[2 * p + 1][sel];
    }
    // coalesced rowpack store: 128*64 floats = 2048 float4 per tile
    #pragma unroll
    for (int w = threadIdx.x; w < DLAT * RPSTRIDE / 4; w += 1024) {
        int i = w >> 4, off = (w & 15) * 4;
        rowpack[t * (DLAT * RPSTRIDE / 4) + w] =
            make_float4(tbuf[i][off], tbuf[i][off + 1], tbuf[i][off + 2], tbuf[i][off + 3]);
    }
}

// ---------------- stage B: kernels + weighted support reduction ----------------
// grid 256 x 1024 (16 waves). half = i-range; wave&7 picks support group.
__global__ __launch_bounds__(1024) void kernelB(
    const float4* __restrict__ scd, const float* __restrict__ sn2,
    const float* __restrict__ wts, const float* __restrict__ rowpack,
    const float* __restrict__ ln2s, float* __restrict__ out)
{
    __shared__ float c01[NSUP][17];     // half0 -> partials for rows 8..15 (8 dot | 8 prod)
    __shared__ float c10[NSUP][17];     // half1 -> partials for rows 0..7
    __shared__ float redw[16][8];

    const int t    = blockIdx.x;
    const int lane = threadIdx.x & 63;
    const int wvu  = __builtin_amdgcn_readfirstlane(threadIdx.x >> 6);  // wave-uniform
    const int half = wvu >> 3;
    const int s    = ((wvu & 7) << 6) | lane;
    const int i0   = half * 64;

    const float* __restrict__ rp0 = rowpack + t * (DLAT * RPSTRIDE) + i0 * RPSTRIDE; // uniform

    v2f dot[8], prod[8];
    #pragma unroll
    for (int q = 0; q < 8; q++) { dot[q] = (v2f)(0.f); prod[q] = (v2f)(1.f); }

    const float4* __restrict__ scds = scd + i0 * NSUP + s;   // per-lane, coalesced
    float4 sc = scds[0];
    #pragma unroll 4
    for (int ii = 0; ii < 64; ii++) {
        float4 scn = (ii < 63) ? scds[(ii + 1) * NSUP] : sc;  // 2-deep prefetch
        const float* rp = rp0 + (ii << 6);                    // uniform -> 3x s_load_dwordx16
        v2f sv = {sc.x, sc.x}, cv = {sc.y, sc.y}, dv = {sc.z, sc.z};
        #pragma unroll
        for (int q = 0; q < 8; q++) {
            v2f lv = {rp[2 * q],      rp[2 * q + 1]};
            v2f av = {rp[16 + 2 * q], rp[16 + 2 * q + 1]};
            v2f bv = {rp[32 + 2 * q], rp[32 + 2 * q + 1]};
            dot[q]  = __builtin_elementwise_fma(lv, sv, dot[q]);
            v2f tt  = __builtin_elementwise_fma(av, cv, bv * dv);
            prod[q] = prod[q] * tt;
        }
        sc = scn;
    }

    // exchange: each half publishes the OTHER half's row-range partials
    if (half == 0) {
        #pragma unroll
        for (int q = 4; q < 8; q++) {
            c01[s][2 * (q - 4)]         = dot[q].x;
            c01[s][2 * (q - 4) + 1]     = dot[q].y;
            c01[s][8 + 2 * (q - 4)]     = prod[q].x;
            c01[s][8 + 2 * (q - 4) + 1] = prod[q].y;
        }
    } else {
        #pragma unroll
        for (int q = 0; q < 4; q++) {
            c10[s][2 * q]         = dot[q].x;
            c10[s][2 * q + 1]     = dot[q].y;
            c10[s][8 + 2 * q]     = prod[q].x;
            c10[s][8 + 2 * q + 1] = prod[q].y;
        }
    }
    __syncthreads();

    // combine own 8 rows
    float dfull[8], pfull[8];
    if (half == 0) {
        #pragma unroll
        for (int q = 0; q < 4; q++) {
            dfull[2 * q]     = dot[q].x + c10[s][2 * q];
            dfull[2 * q + 1] = dot[q].y + c10[s][2 * q + 1];
            pfull[2 * q]     = prod[q].x * c10[s][8 + 2 * q];
            pfull[2 * q + 1] = prod[q].y * c10[s][8 + 2 * q + 1];
        }
    } else {
        #pragma unroll
        for (int q = 4; q < 8; q++) {
            dfull[2 * (q - 4)]     = dot[q].x + c01[s][2 * (q - 4)];
            dfull[2 * (q - 4) + 1] = dot[q].y + c01[s][2 * (q - 4) + 1];
            pfull[2 * (q - 4)]     = prod[q].x * c01[s][8 + 2 * (q - 4)];
            pfull[2 * (q - 4) + 1] = prod[q].y * c01[s][8 + 2 * (q - 4) + 1];
        }
    }

    float sn  = sn2[s];
    float wgt = wts[s];
    const float* lr = ln2s + ((t << 4) | (half << 3));     // uniform -> s_load_dwordx8
    #pragma unroll
    for (int rr = 0; rr < 8; rr++) {
        float sq = lr[rr] + sn - 2.f * dfull[rr];
        float kc = __expf(-sq);
        float p  = pfull[rr];
        float v  = (0.5f * kc + 0.5f * (p * p)) * wgt;
        for (int off = 32; off; off >>= 1) v += __shfl_down(v, off);
        if (lane == 0) redw[wvu][rr] = v;
    }
    __syncthreads();
    if (threadIdx.x < BR) {
        int h = threadIdx.x >> 3, rr = threadIdx.x & 7;
        float o = 0.f;
        #pragma unroll
        for (int w = 0; w < 8; w++) o += redw[h * 8 + w][rr];
        out[t * BR + h * 8 + rr] = o;
    }
}

// ---------------- launch ----------------
extern "C" void kernel_launch(void* const* d_in, const int* in_sizes, int n_in,
                              void* d_out, int out_size, void* d_ws, size_t ws_size,
                              hipStream_t stream) {
    const float* x       = (const float*)d_in[0];
    const float* W1      = (const float*)d_in[1];
    const float* b1      = (const float*)d_in[2];
    const float* W2      = (const float*)d_in[3];
    const float* b2      = (const float*)d_in[4];
    const float* support = (const float*)d_in[5];
    const float* wts     = (const float*)d_in[6];
    float* out = (float*)d_out;

    float* ws      = (float*)d_ws;
    float* W1T     = ws;                        // 32768
    float* W2T     = W1T + 32768;               // 65536
    float* xpack   = W2T + 65536;               // 262144
    float* hpack   = xpack + 262144;            // 2097152
    float* rowpack = hpack + 2097152;           // 2097152 (padded rows, 16B-aligned)
    float* ln2s    = rowpack + 2097152;         // 4096
    float* sn2     = ln2s + 4096;               // 512
    float4* scd    = (float4*)(sn2 + 512);      // 65536 float4 (16B-aligned offset)

    prep_kernel <<<512,  512, 0, stream>>>(x, W1, W2, support, W1T, W2T, xpack, scd, sn2);
    gemm1_kernel<<<NTILE, 512, 0, stream>>>(W1T, b1, xpack, hpack);
    gemm2_kernel<<<NTILE, 1024, 0, stream>>>(W2T, b2, hpack, (float4*)rowpack, ln2s);
    kernelB     <<<NTILE, 1024, 0, stream>>>(scd, sn2, wts, rowpack, ln2s, out);
}